// Round 16
// baseline (247.025 us; speedup 1.0000x reference)
//
#include <hip/hip_runtime.h>
#include <hip/hip_bf16.h>
#include <math.h>

// float32(np.e) exactly: 0x402DF854
#define E32 2.7182817459106445f

__device__ __forceinline__ unsigned long long packkey(float vf, int idx) {
  unsigned u = __float_as_uint(vf);
  u = (u & 0x80000000u) ? ~u : (u | 0x80000000u);
  return (((unsigned long long)u) << 32) | (unsigned)idx;
}
__device__ __forceinline__ float unpackval(unsigned long long k) {
  unsigned m = (unsigned)(k >> 32);
  m = (m & 0x80000000u) ? (m ^ 0x80000000u) : ~m;
  return __uint_as_float(m);
}

// ---------------------------------------------------------------------------
// Stage 1: one tanh per thread; store tanh value + per-block max|tanh|.
// ---------------------------------------------------------------------------
__global__ __launch_bounds__(256) void tanh_max_kernel(
    const float* __restrict__ w2, const float* __restrict__ w3,
    const float* __restrict__ w4, const float* __restrict__ w5,
    float* __restrict__ tanhbuf, float* __restrict__ partials) {
  int blk = blockIdx.x;
  const float* w; int base_blk, tbase;
  if (blk < 36)       { w = w2; base_blk = 0;   tbase = 0; }
  else if (blk < 72)  { w = w3; base_blk = 36;  tbase = 9216; }
  else if (blk < 144) { w = w4; base_blk = 72;  tbase = 18432; }
  else                { w = w5; base_blk = 144; tbase = 36864; }
  int i = (blk - base_blk) * 256 + threadIdx.x;
  float t = tanhf(w[i]);
  tanhbuf[tbase + i] = t;
  __shared__ float red[256];
  red[threadIdx.x] = fabsf(t);
  __syncthreads();
  for (int s = 128; s > 0; s >>= 1) {
    if (threadIdx.x < s) red[threadIdx.x] = fmaxf(red[threadIdx.x], red[threadIdx.x + s]);
    __syncthreads();
  }
  if (threadIdx.x == 0) partials[blk] = red[0];
}

// ---------------------------------------------------------------------------
// Stage 2 (fused): blocks [0,288) quantize; blocks [288,448) transpose wfc.
// ---------------------------------------------------------------------------
__global__ __launch_bounds__(256) void quantT_kernel(
    const float* __restrict__ tanhbuf, const float* __restrict__ partials,
    float* __restrict__ q2, float* __restrict__ q3,
    float* __restrict__ q4, float* __restrict__ q5,
    const float* __restrict__ wfc, float* __restrict__ wfcT) {
  int blk = blockIdx.x;
  if (blk >= 288) {
    int o = (blk - 288) * 256 + threadIdx.x;
    if (o < 40960) {
      int n = o / 10, f = o % 10;
      wfcT[o] = wfc[f * 4096 + n];
    }
    return;
  }
  float* dst; int base_blk, tbase, pb0, pb1, F, N;
  if (blk < 36)       { dst = q2; base_blk = 0;   tbase = 0;     pb0 = 0;   pb1 = 36;  F = 32; N = 288; }
  else if (blk < 72)  { dst = q3; base_blk = 36;  tbase = 9216;  pb0 = 36;  pb1 = 72;  F = 32; N = 288; }
  else if (blk < 144) { dst = q4; base_blk = 72;  tbase = 18432; pb0 = 72;  pb1 = 144; F = 64; N = 288; }
  else                { dst = q5; base_blk = 144; tbase = 36864; pb0 = 144; pb1 = 288; F = 64; N = 576; }
  __shared__ float red[256];
  float mx = 0.0f;
  for (int j = pb0 + threadIdx.x; j < pb1; j += 256) mx = fmaxf(mx, partials[j]);
  red[threadIdx.x] = mx;
  __syncthreads();
  for (int s = 128; s > 0; s >>= 1) {
    if (threadIdx.x < s) red[threadIdx.x] = fmaxf(red[threadIdx.x], red[threadIdx.x + s]);
    __syncthreads();
  }
  float a = red[0];
  int i = (blk - base_blk) * 256 + threadIdx.x;
  float t = tanhbuf[tbase + i];
  int f = i / N, n = i % N;
  float r = fminf(fmaxf(t / a, -1.0f), 1.0f) * 127.0f;
  dst[n * F + f] = rintf(r) * a / 127.0f;
}

// ---------------------------------------------------------------------------
// conv1 + BN + ReLU + maxpool2 + min(.,1) + exp
// ---------------------------------------------------------------------------
__global__ __launch_bounds__(256) void conv1_kernel(
    const float* __restrict__ inp, const float* __restrict__ w,
    const float* __restrict__ g, const float* __restrict__ bb,
    const float* __restrict__ m, const float* __restrict__ vv,
    float* __restrict__ z1) {
  int idx = blockIdx.x * 256 + threadIdx.x;
  if (idx >= 8 * 32 * 32 * 32) return;
  int x = idx & 31, y = (idx >> 5) & 31, c = (idx >> 10) & 31, b = idx >> 15;
  float scale = g[c] / sqrtf(vv[c] + 1e-5f);
  float bias = bb[c];
  float mean = m[c];
  float mx = -3.402823466e38f;
  for (int dy = 0; dy < 2; ++dy) {
    for (int dx = 0; dx < 2; ++dx) {
      int oy = 2 * y + dy, ox = 2 * x + dx;
      float acc = 0.0f;
      for (int kh = 0; kh < 5; ++kh) {
        int r = oy + kh - 2;
        if (r < 0 || r >= 64) continue;
        for (int kw = 0; kw < 5; ++kw) {
          int cc2 = ox + kw - 2;
          if (cc2 < 0 || cc2 >= 64) continue;
          acc += w[c * 25 + kh * 5 + kw] * inp[(b * 64 + r) * 64 + cc2];
        }
      }
      float xs = (acc - mean) * scale + bias;
      xs = fmaxf(xs, 0.0f);
      mx = fmaxf(mx, xs);
    }
  }
  mx = fminf(mx, 1.0f);
  z1[idx] = (mx == 1.0f) ? E32 : expf(mx);
}

// ---------------------------------------------------------------------------
// min_pool3 (3x3, stride 2, pad 1 w/ 1e5)
// ---------------------------------------------------------------------------
__global__ __launch_bounds__(256) void mp3_kernel(
    const float* __restrict__ in, float* __restrict__ out, int BC, int H) {
  int OH = H >> 1;
  int total = BC * OH * OH;
  int idx = blockIdx.x * 256 + threadIdx.x;
  if (idx >= total) return;
  int j = idx % OH, i = (idx / OH) % OH, bc = idx / (OH * OH);
  float mn = 100000.0f;
  for (int di = 0; di < 3; ++di) {
    int r = 2 * i - 1 + di;
    if (r < 0 || r >= H) continue;
    for (int dj = 0; dj < 3; ++dj) {
      int cc = 2 * j - 1 + dj;
      if (cc < 0 || cc >= H) continue;
      mn = fminf(mn, in[bc * H * H + r * H + cc]);
    }
  }
  out[idx] = mn;
}

// min_pool3 over (a*b) computed on the fly
__global__ __launch_bounds__(256) void mp3mul_kernel(
    const float* __restrict__ a, const float* __restrict__ b2,
    float* __restrict__ out, int BC, int H) {
  int OH = H >> 1;
  int total = BC * OH * OH;
  int idx = blockIdx.x * 256 + threadIdx.x;
  if (idx >= total) return;
  int j = idx % OH, i = (idx / OH) % OH, bc = idx / (OH * OH);
  float mn = 100000.0f;
  for (int di = 0; di < 3; ++di) {
    int r = 2 * i - 1 + di;
    if (r < 0 || r >= H) continue;
    for (int dj = 0; dj < 3; ++dj) {
      int cc = 2 * j - 1 + dj;
      if (cc < 0 || cc >= H) continue;
      int q = bc * H * H + r * H + cc;
      mn = fminf(mn, __fmul_rn(a[q], b2[q]));
    }
  }
  out[idx] = mn;
}

// ---------------------------------------------------------------------------
// t_conv: CB blocks per patch, each handling FB = F/CB output channels.
//  Phase 1: register bitonic sort (duplicated across the CB blocks — cheap)
//  Phase 2: carry-replay scan over FB channels (bit-exact per channel).
// ---------------------------------------------------------------------------
template <int CIN, int F, int FB, int S, int HIN, bool MUL>
__global__ __launch_bounds__(512, 1) void tconv_kernel(
    const float* __restrict__ in, const float* __restrict__ in2,
    const float* __restrict__ wqt, float* __restrict__ out, float MST) {
  constexpr int N = CIN * 9;
  constexpr int NP = (N <= 512) ? 512 : 1024;
  constexpr int KP = NP / 512;
  constexpr int OH = (HIN - 1) / S + 1;
  constexpr int P = OH * OH;
  constexpr int T = 512;
  constexpr int NCH = N / 32;
  constexpr int CB = F / FB;

  __shared__ __align__(16) unsigned long long pk[NP];
  __shared__ float sval[N + 1];
  __shared__ unsigned short sidx[N];
  __shared__ float wbuf[2][32 * FB];
  __shared__ float wc[NCH][FB];
  __shared__ float iwc[NCH][FB];
  __shared__ float pmin[FB * NCH];

  int blk = blockIdx.x;
  int patch = blk / CB, fslice = blk % CB;
  int f_base = fslice * FB;
  int b = patch / P, p = patch % P;
  int ph = p / OH, pw = p % OH;
  int tid = threadIdx.x;

  // Phase 0: patch keys (+inf pad beyond N)
  for (int n = tid; n < NP; n += T) {
    if (n < N) {
      int c = n / 9, kk = n % 9, kh = kk / 3, kw = kk % 3;
      int r = ph * S + kh - 1, cc = pw * S + kw - 1;
      float v = 0.0f;
      if (r >= 0 && r < HIN && cc >= 0 && cc < HIN) {
        int q = ((b * CIN + c) * HIN + r) * HIN + cc;
        v = MUL ? __fmul_rn(in[q], in2[q]) : in[q];
      }
      pk[n] = packkey((v < 0.1f) ? MST : v, n);
    } else {
      pk[n] = ~0ull;
    }
  }
  if (tid == 0) sval[N] = 1.0f;
  __syncthreads();

  // Phase 1: bitonic sort
  if constexpr (KP == 1) {
    unsigned long long k0 = pk[tid];
    __syncthreads();
    for (int lk = 1; lk <= 9; ++lk) {
      for (int lj = lk - 1; lj >= 0; --lj) {
        int j = 1 << lj;
        bool up = ((tid >> lk) & 1) == 0;
        bool wmin = (((tid & j) == 0) == up);
        unsigned long long o;
        if (lj >= 6) {
          pk[tid] = k0;
          __syncthreads();
          o = pk[tid ^ j];
          __syncthreads();
        } else {
          o = __shfl_xor(k0, j, 64);
        }
        k0 = wmin ? (k0 < o ? k0 : o) : (k0 > o ? k0 : o);
      }
    }
    if (tid < N) {
      sval[tid] = unpackval(k0);
      sidx[tid] = (unsigned short)(k0 & 0xffffull);
    }
  } else {
    unsigned long long k0 = pk[2 * tid], k1 = pk[2 * tid + 1];
    __syncthreads();
    for (int lk = 1; lk <= 10; ++lk) {
      for (int lj = lk - 1; lj >= 0; --lj) {
        bool up = ((tid >> (lk - 1)) & 1) == 0;
        if (lj == 0) {
          if ((k0 > k1) == up) { unsigned long long t2 = k0; k0 = k1; k1 = t2; }
        } else {
          int tj = 1 << (lj - 1);
          bool wmin = (((tid & tj) == 0) == up);
          unsigned long long o0, o1;
          if (lj >= 7) {
            pk[tid] = k0; pk[512 + tid] = k1;
            __syncthreads();
            o0 = pk[tid ^ tj]; o1 = pk[512 + (tid ^ tj)];
            __syncthreads();
          } else {
            o0 = __shfl_xor(k0, tj, 64);
            o1 = __shfl_xor(k1, tj, 64);
          }
          k0 = wmin ? (k0 < o0 ? k0 : o0) : (k0 > o0 ? k0 : o0);
          k1 = wmin ? (k1 < o1 ? k1 : o1) : (k1 > o1 ? k1 : o1);
        }
      }
    }
    int i0 = tid * 2;
    if (i0 < N) {
      sval[i0] = unpackval(k0);
      sidx[i0] = (unsigned short)(k0 & 0xffffull);
    }
    if (i0 + 1 < N) {
      sval[i0 + 1] = unpackval(k1);
      sidx[i0 + 1] = (unsigned short)(k1 & 0xffffull);
    }
  }
  __syncthreads();

  // Phase 2a: stage chunk 0 (all threads)
  for (int t = tid; t < 32 * FB; t += T) {
    int q = t / FB, f = t % FB;
    wbuf[0][t] = wqt[(int)sidx[q] * F + f_base + f];
  }
  __syncthreads();

  // Phase 2b: pass A — wave 0 chains, other waves stage next chunk
  float wsum = 0.0f, iwsum = 0.0f;
  for (int c = 0; c < NCH; ++c) {
    if (tid >= 64 && c + 1 < NCH) {
      int i0n = (c + 1) * 32;
      float* nb = wbuf[(c + 1) & 1];
      for (int t = tid - 64; t < 32 * FB; t += (T - 64)) {
        int q = t / FB, f = t % FB;
        nb[t] = wqt[(int)sidx[i0n + q] * F + f_base + f];
      }
    }
    if (tid < FB) {
      const float* wb = wbuf[c & 1];
      wc[c][tid] = wsum;
      iwc[c][tid] = iwsum;
      int i0 = c * 32;
#pragma unroll
      for (int q0 = 0; q0 < 32; q0 += 8) {
        float w8[8], s8[8];
#pragma unroll
        for (int r = 0; r < 8; ++r) {
          w8[r] = wb[(q0 + r) * FB + tid];
          s8[r] = sval[i0 + q0 + r];
        }
#pragma unroll
        for (int r = 0; r < 8; ++r) {
          wsum = __fadd_rn(wsum, w8[r]);
          iwsum = __fadd_rn(iwsum, __fmul_rn(s8[r], w8[r]));
        }
      }
    }
    __syncthreads();
  }

  // Phase 2c: replay — NCH*FB parallel tasks, bit-exact per element
  for (int task = tid; task < NCH * FB; task += T) {
    int c = task / FB, f = task % FB;
    float ws = wc[c][f], iws = iwc[c][f], omin = 3.402823466e38f;
    int i0 = c * 32;
#pragma unroll
    for (int q0 = 0; q0 < 32; q0 += 8) {
      float wv8[8], sv8[8], nv8[8];
#pragma unroll
      for (int r = 0; r < 8; ++r) {
        int i = i0 + q0 + r;
        wv8[r] = wqt[(int)sidx[i] * F + f_base + f];
        sv8[r] = sval[i];
        nv8[r] = sval[i + 1];
      }
#pragma unroll
      for (int r = 0; r < 8; ++r) {
        ws = __fadd_rn(ws, wv8[r]);
        iws = __fadd_rn(iws, __fmul_rn(sv8[r], wv8[r]));
        float den = fminf(fmaxf(__fadd_rn(ws, -1.0f), 1e-10f), 1e10f);
        float oa = iws / den;
        float o = (ws < 1.0f) ? MST : oa;
        o = (o < sv8[r]) ? MST : o;
        o = (o > nv8[r]) ? MST : o;  // t_linear_c: strict >
        omin = fminf(omin, o);
      }
    }
    pmin[f * NCH + c] = omin;
  }
  __syncthreads();

  // Phase 2d: min across chunks (order-free), write out
  if (tid < FB) {
    float m2 = pmin[tid * NCH];
#pragma unroll
    for (int c = 1; c < NCH; ++c) m2 = fminf(m2, pmin[tid * NCH + c]);
    out[(b * F + f_base + tid) * P + p] = m2;
  }
}

// ---------------------------------------------------------------------------
// Bitonic pass, fully compile-time specialized (LK = stage, LJ = pass).
// ---------------------------------------------------------------------------
template <int LK, int LJ>
__device__ __forceinline__ void bpass(unsigned long long (&k)[8],
                                      unsigned long long* keys,
                                      int tid, int lane) {
  if constexpr (LJ >= 9) {
    constexpr int pm = 1 << (LJ - 3);
#pragma unroll
    for (int m = 0; m < 8; ++m) keys[m * 512 + tid] = k[m];
    __syncthreads();
    bool lower = ((tid & pm) == 0);
    bool up = (((tid >> (LK - 3)) & 1) == 0);
    bool wmin = (lower == up);
#pragma unroll
    for (int m = 0; m < 8; ++m) {
      unsigned long long o = keys[m * 512 + (tid ^ pm)];
      unsigned long long mine = k[m];
      k[m] = wmin ? (mine < o ? mine : o) : (mine > o ? mine : o);
    }
    __syncthreads();
  } else if constexpr (LJ >= 3) {
    constexpr int lm = 1 << (LJ - 3);
    bool lower = ((lane & lm) == 0);
    bool up = (((tid >> (LK - 3)) & 1) == 0);
    bool wmin = (lower == up);
#pragma unroll
    for (int m = 0; m < 8; ++m) {
      unsigned long long o = __shfl_xor(k[m], lm, 64);
      unsigned long long mine = k[m];
      k[m] = wmin ? (mine < o ? mine : o) : (mine > o ? mine : o);
    }
  } else {
    constexpr int j = 1 << LJ;
#pragma unroll
    for (int m = 0; m < 8; ++m) {
      if ((m & j) == 0) {
        int i = (tid << 3) + m;
        bool up = (((i >> LK) & 1) == 0);
        unsigned long long a = k[m], c2 = k[m | j];
        if ((a > c2) == up) { k[m] = c2; k[m | j] = a; }
      }
    }
  }
}

template <int LK, int LJ>
__device__ __forceinline__ void bpasses(unsigned long long (&k)[8],
                                        unsigned long long* keys,
                                        int tid, int lane) {
  bpass<LK, LJ>(k, keys, tid, lane);
  if constexpr (LJ > 0) bpasses<LK, LJ - 1>(k, keys, tid, lane);
}

template <int LK>
__device__ __forceinline__ void bstages(unsigned long long (&k)[8],
                                        unsigned long long* keys,
                                        int tid, int lane) {
  bpasses<LK, LK - 1>(k, keys, tid, lane);
  if constexpr (LK < 12) bstages<LK + 1>(k, keys, tid, lane);
}

// ---------------------------------------------------------------------------
// FC sort: 8 blocks x 512, unrolled register bitonic; writes sval/sidx.
// ---------------------------------------------------------------------------
__global__ __launch_bounds__(512, 1) void fc_sort_kernel(
    const float* __restrict__ z5, const float* __restrict__ m3,
    float* __restrict__ svalG, unsigned short* __restrict__ sidxG) {
  __shared__ __align__(16) unsigned long long keys[4096];
  int b = blockIdx.x, tid = threadIdx.x, lane = tid & 63;

  unsigned long long k[8];
  {
    int c = tid >> 3, p0 = (tid << 3) & 63;
    const float4* z4p = (const float4*)(z5 + (b * 64 + c) * 64 + p0);
    const float4* m4p = (const float4*)(m3 + (b * 32 + (c & 31)) * 64 + p0);
    float4 za = z4p[0], zb = z4p[1], ma = m4p[0], mb = m4p[1];
    int n0 = tid << 3;
    k[0] = packkey(__fmul_rn(za.x, ma.x), n0 + 0);
    k[1] = packkey(__fmul_rn(za.y, ma.y), n0 + 1);
    k[2] = packkey(__fmul_rn(za.z, ma.z), n0 + 2);
    k[3] = packkey(__fmul_rn(za.w, ma.w), n0 + 3);
    k[4] = packkey(__fmul_rn(zb.x, mb.x), n0 + 4);
    k[5] = packkey(__fmul_rn(zb.y, mb.y), n0 + 5);
    k[6] = packkey(__fmul_rn(zb.z, mb.z), n0 + 6);
    k[7] = packkey(__fmul_rn(zb.w, mb.w), n0 + 7);
  }

  bstages<1>(k, keys, tid, lane);

  {
    float4 v0, v1;
    v0.x = unpackval(k[0]); v0.y = unpackval(k[1]);
    v0.z = unpackval(k[2]); v0.w = unpackval(k[3]);
    v1.x = unpackval(k[4]); v1.y = unpackval(k[5]);
    v1.z = unpackval(k[6]); v1.w = unpackval(k[7]);
    float* svalRow = svalG + b * 4104;
    ((float4*)svalRow)[tid * 2] = v0;
    ((float4*)svalRow)[tid * 2 + 1] = v1;
    ushort si[8];
#pragma unroll
    for (int m = 0; m < 8; ++m) si[m] = (unsigned short)(k[m] & 0xffffull);
    ((ulong2*)(sidxG + b * 4096))[tid] = *(ulong2*)si;
    if (tid == 0) svalRow[4096] = 1.0f;
  }
}

// ---------------------------------------------------------------------------
// FC scan v3: 80 blocks (batch x neuron) x 512 threads. (unchanged — passing)
// ---------------------------------------------------------------------------
__global__ __launch_bounds__(512, 1) void fc_scan2_kernel(
    const float* __restrict__ svalG, const unsigned short* __restrict__ sidxG,
    const float* __restrict__ wfcT, float* __restrict__ out) {
  constexpr int NN = 4096;
  __shared__ __align__(16) float sval[NN + 1];
  __shared__ __align__(16) float pairs[NN * 2];
  __shared__ float wc[128], iwc[128];
  __shared__ float pmin[128];

  int blk = blockIdx.x;
  int b = blk / 10, f = blk % 10;
  int tid = threadIdx.x;
  const float* svalRow = svalG + b * 4104;

  for (int t = tid; t < 1024; t += 512)
    ((float4*)sval)[t] = ((const float4*)svalRow)[t];
  if (tid == 0) sval[NN] = svalRow[4096];

  ushort si[8];
  *(ulong2*)si = ((const ulong2*)(sidxG + b * 4096))[tid];
  float wv[8];
#pragma unroll
  for (int u = 0; u < 8; ++u) wv[u] = wfcT[(int)si[u] * 10 + f];
  __syncthreads();

  {
    int n0 = tid * 8;
    float4 pw[4];
#pragma unroll
    for (int u = 0; u < 4; ++u) {
      float wa = wv[2 * u], wb2 = wv[2 * u + 1];
      pw[u].x = wa;
      pw[u].y = __fmul_rn(sval[n0 + 2 * u], wa);
      pw[u].z = wb2;
      pw[u].w = __fmul_rn(sval[n0 + 2 * u + 1], wb2);
    }
#pragma unroll
    for (int u = 0; u < 4; ++u) ((float4*)pairs)[tid * 4 + u] = pw[u];
  }
  __syncthreads();

  if (tid == 0) {
    float wsum = 0.0f, iwsum = 0.0f;
    float4 A[16], B[16];
    auto LD_A = [&](int c) {
      const float4* p4 = (const float4*)pairs + c * 16;
#pragma unroll
      for (int q = 0; q < 16; ++q) A[q] = p4[q];
    };
    auto LD_B = [&](int c) {
      const float4* p4 = (const float4*)pairs + c * 16;
#pragma unroll
      for (int q = 0; q < 16; ++q) B[q] = p4[q];
    };
    auto ACC_A = [&]() {
#pragma unroll
      for (int q = 0; q < 16; ++q) {
        wsum = __fadd_rn(wsum, A[q].x); iwsum = __fadd_rn(iwsum, A[q].y);
        wsum = __fadd_rn(wsum, A[q].z); iwsum = __fadd_rn(iwsum, A[q].w);
      }
    };
    auto ACC_B = [&]() {
#pragma unroll
      for (int q = 0; q < 16; ++q) {
        wsum = __fadd_rn(wsum, B[q].x); iwsum = __fadd_rn(iwsum, B[q].y);
        wsum = __fadd_rn(wsum, B[q].z); iwsum = __fadd_rn(iwsum, B[q].w);
      }
    };
    LD_A(0);
    for (int c = 0; c < 128; c += 2) {
      wc[c] = wsum; iwc[c] = iwsum;
      if (c + 1 < 128) LD_B(c + 1);
      ACC_A();
      wc[c + 1] = wsum; iwc[c + 1] = iwsum;
      if (c + 2 < 128) LD_A(c + 2);
      ACC_B();
    }
  }
  __syncthreads();

  const float MST = 4.0f * E32;
  if (tid < 128) {
    float ws = wc[tid], iws = iwc[tid], omin = 3.402823466e38f;
    int i0 = tid * 32;
    for (int q0 = 0; q0 < 32; q0 += 8) {
      float w8[8], m8[8], sv8[8], nv8[8];
#pragma unroll
      for (int r = 0; r < 8; ++r) {
        int i = i0 + q0 + r;
        w8[r] = pairs[2 * i];
        m8[r] = pairs[2 * i + 1];
        sv8[r] = sval[i];
        nv8[r] = sval[i + 1];
      }
#pragma unroll
      for (int r = 0; r < 8; ++r) {
        ws = __fadd_rn(ws, w8[r]);
        iws = __fadd_rn(iws, m8[r]);
        float den = fminf(fmaxf(__fadd_rn(ws, -1.0f), 1e-10f), 1e10f);
        float oa = iws / den;
        float o = (ws < 1.0f) ? MST : oa;
        o = (o < sv8[r]) ? MST : o;
        o = (o >= nv8[r]) ? MST : o;  // t_linear: >=
        omin = fminf(omin, o);
      }
    }
    pmin[tid] = omin;
  }
  __syncthreads();

  if (tid == 0) {
    float m = pmin[0];
    for (int c = 1; c < 128; ++c) m = fminf(m, pmin[c]);
    out[b * 10 + f] = m;
  }
}

// ---------------------------------------------------------------------------
extern "C" void kernel_launch(void* const* d_in, const int* in_sizes, int n_in,
                              void* d_out, int out_size, void* d_ws, size_t ws_size,
                              hipStream_t stream) {
  const float* inp   = (const float*)d_in[0];
  const float* w1    = (const float*)d_in[1];
  const float* bn_g  = (const float*)d_in[2];
  const float* bn_b  = (const float*)d_in[3];
  const float* bn_m  = (const float*)d_in[4];
  const float* bn_v  = (const float*)d_in[5];
  const float* w2    = (const float*)d_in[6];
  const float* w3    = (const float*)d_in[7];
  const float* w4    = (const float*)d_in[8];
  const float* w5    = (const float*)d_in[9];
  const float* wfc   = (const float*)d_in[10];
  float* out = (float*)d_out;

  float* ws = (float*)d_ws;
  float* wq2 = ws + 16;          // 9216
  float* wq3 = wq2 + 9216;       // 9216
  float* wq4 = wq3 + 9216;       // 18432
  float* wq5 = wq4 + 18432;      // 36864
  float* z1  = wq5 + 36864;      // 262144
  float* m1  = z1 + 262144;      // 65536
  float* z2  = m1 + 65536;       // 65536
  float* z3  = z2 + 65536;       // 65536
  float* m3  = z3 + 65536;       // 16384
  float* z4  = m3 + 16384;       // 32768
  float* z5  = z4 + 32768;       // 32768
  float* tanhbuf  = z5 + 32768;  // 73728
  float* partials = tanhbuf + 73728;  // 288 (pad 512)
  float* wfcT = partials + 512;  // 40960
  float* svalG = wfcT + 40960;   // 8*4104 = 32832
  unsigned short* sidxG = (unsigned short*)(svalG + 32832);  // 8*4096 u16

  tanh_max_kernel<<<288, 256, 0, stream>>>(w2, w3, w4, w5, tanhbuf, partials);
  quantT_kernel<<<448, 256, 0, stream>>>(tanhbuf, partials, wq2, wq3, wq4, wq5, wfc, wfcT);

  conv1_kernel<<<1024, 256, 0, stream>>>(inp, w1, bn_g, bn_b, bn_m, bn_v, z1);
  mp3_kernel<<<256, 256, 0, stream>>>(z1, m1, 8 * 32, 32);

  // layers 2/3: F=32, one block per patch (CB=1)
  tconv_kernel<32, 32, 32, 2, 32, false><<<8 * 256, 512, 0, stream>>>(z1, nullptr, wq2, z2, E32);
  tconv_kernel<32, 32, 32, 1, 16, false><<<8 * 256, 512, 0, stream>>>(z2, nullptr, wq3, z3, E32);
  mp3mul_kernel<<<64, 256, 0, stream>>>(z3, m1, m3, 8 * 32, 16);
  // layers 4/5: F=64 split across CB=2 blocks (FB=32) -> 1024 blocks each
  tconv_kernel<32, 64, 32, 2, 16, true><<<8 * 64 * 2, 512, 0, stream>>>(z3, m1, wq4, z4, 2.0f * E32);
  tconv_kernel<64, 64, 32, 1, 8, false><<<8 * 64 * 2, 512, 0, stream>>>(z4, nullptr, wq5, z5, 2.0f * E32);

  fc_sort_kernel<<<8, 512, 0, stream>>>(z5, m3, svalG, sidxG);
  fc_scan2_kernel<<<80, 512, 0, stream>>>(svalG, sidxG, wfcT, out);
}

// Round 17
// 224.783 us; speedup vs baseline: 1.0989x; 1.0989x over previous
//
#include <hip/hip_runtime.h>
#include <hip/hip_bf16.h>
#include <math.h>

// float32(np.e) exactly: 0x402DF854
#define E32 2.7182817459106445f

__device__ __forceinline__ unsigned long long packkey(float vf, int idx) {
  unsigned u = __float_as_uint(vf);
  u = (u & 0x80000000u) ? ~u : (u | 0x80000000u);
  return (((unsigned long long)u) << 32) | (unsigned)idx;
}
__device__ __forceinline__ float unpackval(unsigned long long k) {
  unsigned m = (unsigned)(k >> 32);
  m = (m & 0x80000000u) ? (m ^ 0x80000000u) : ~m;
  return __uint_as_float(m);
}

// ---------------------------------------------------------------------------
// pre1 (fused): blocks [0,288) tanh+max partials; blocks [288,1312) conv1.
// ---------------------------------------------------------------------------
__global__ __launch_bounds__(256) void pre1_kernel(
    const float* __restrict__ w2, const float* __restrict__ w3,
    const float* __restrict__ w4, const float* __restrict__ w5,
    float* __restrict__ tanhbuf, float* __restrict__ partials,
    const float* __restrict__ inp, const float* __restrict__ w1,
    const float* __restrict__ g, const float* __restrict__ bb,
    const float* __restrict__ m, const float* __restrict__ vv,
    float* __restrict__ z1) {
  int blk = blockIdx.x;
  if (blk < 288) {
    const float* w; int base_blk, tbase;
    if (blk < 36)       { w = w2; base_blk = 0;   tbase = 0; }
    else if (blk < 72)  { w = w3; base_blk = 36;  tbase = 9216; }
    else if (blk < 144) { w = w4; base_blk = 72;  tbase = 18432; }
    else                { w = w5; base_blk = 144; tbase = 36864; }
    int i = (blk - base_blk) * 256 + threadIdx.x;
    float t = tanhf(w[i]);
    tanhbuf[tbase + i] = t;
    __shared__ float red[256];
    red[threadIdx.x] = fabsf(t);
    __syncthreads();
    for (int s = 128; s > 0; s >>= 1) {
      if (threadIdx.x < s) red[threadIdx.x] = fmaxf(red[threadIdx.x], red[threadIdx.x + s]);
      __syncthreads();
    }
    if (threadIdx.x == 0) partials[blk] = red[0];
    return;
  }
  // conv1 + BN + ReLU + maxpool2 + min(.,1) + exp
  int idx = (blk - 288) * 256 + threadIdx.x;
  if (idx >= 8 * 32 * 32 * 32) return;
  int x = idx & 31, y = (idx >> 5) & 31, c = (idx >> 10) & 31, b = idx >> 15;
  float scale = g[c] / sqrtf(vv[c] + 1e-5f);
  float bias = bb[c];
  float mean = m[c];
  float mx = -3.402823466e38f;
  for (int dy = 0; dy < 2; ++dy) {
    for (int dx = 0; dx < 2; ++dx) {
      int oy = 2 * y + dy, ox = 2 * x + dx;
      float acc = 0.0f;
      for (int kh = 0; kh < 5; ++kh) {
        int r = oy + kh - 2;
        if (r < 0 || r >= 64) continue;
        for (int kw = 0; kw < 5; ++kw) {
          int cc2 = ox + kw - 2;
          if (cc2 < 0 || cc2 >= 64) continue;
          acc += w1[c * 25 + kh * 5 + kw] * inp[(b * 64 + r) * 64 + cc2];
        }
      }
      float xs = (acc - mean) * scale + bias;
      xs = fmaxf(xs, 0.0f);
      mx = fmaxf(mx, xs);
    }
  }
  mx = fminf(mx, 1.0f);
  z1[idx] = (mx == 1.0f) ? E32 : expf(mx);
}

// ---------------------------------------------------------------------------
// pre2 (fused): blocks [0,288) quantize; [288,448) transpose wfc;
//               [448,704) min_pool3 of z1 -> m1.
// ---------------------------------------------------------------------------
__global__ __launch_bounds__(256) void pre2_kernel(
    const float* __restrict__ tanhbuf, const float* __restrict__ partials,
    float* __restrict__ q2, float* __restrict__ q3,
    float* __restrict__ q4, float* __restrict__ q5,
    const float* __restrict__ wfc, float* __restrict__ wfcT,
    const float* __restrict__ z1, float* __restrict__ m1) {
  int blk = blockIdx.x;
  if (blk >= 448) {
    // mp3: BC=256, H=32
    int idx = (blk - 448) * 256 + threadIdx.x;
    if (idx >= 65536) return;
    int OH = 16;
    int j = idx % OH, i = (idx / OH) % OH, bc = idx / (OH * OH);
    float mn = 100000.0f;
    for (int di = 0; di < 3; ++di) {
      int r = 2 * i - 1 + di;
      if (r < 0 || r >= 32) continue;
      for (int dj = 0; dj < 3; ++dj) {
        int cc = 2 * j - 1 + dj;
        if (cc < 0 || cc >= 32) continue;
        mn = fminf(mn, z1[bc * 1024 + r * 32 + cc]);
      }
    }
    m1[idx] = mn;
    return;
  }
  if (blk >= 288) {
    int o = (blk - 288) * 256 + threadIdx.x;
    if (o < 40960) {
      int n = o / 10, f = o % 10;
      wfcT[o] = wfc[f * 4096 + n];
    }
    return;
  }
  float* dst; int base_blk, tbase, pb0, pb1, F, N;
  if (blk < 36)       { dst = q2; base_blk = 0;   tbase = 0;     pb0 = 0;   pb1 = 36;  F = 32; N = 288; }
  else if (blk < 72)  { dst = q3; base_blk = 36;  tbase = 9216;  pb0 = 36;  pb1 = 72;  F = 32; N = 288; }
  else if (blk < 144) { dst = q4; base_blk = 72;  tbase = 18432; pb0 = 72;  pb1 = 144; F = 64; N = 288; }
  else                { dst = q5; base_blk = 144; tbase = 36864; pb0 = 144; pb1 = 288; F = 64; N = 576; }
  __shared__ float red[256];
  float mx = 0.0f;
  for (int j = pb0 + threadIdx.x; j < pb1; j += 256) mx = fmaxf(mx, partials[j]);
  red[threadIdx.x] = mx;
  __syncthreads();
  for (int s = 128; s > 0; s >>= 1) {
    if (threadIdx.x < s) red[threadIdx.x] = fmaxf(red[threadIdx.x], red[threadIdx.x + s]);
    __syncthreads();
  }
  float a = red[0];
  int i = (blk - base_blk) * 256 + threadIdx.x;
  float t = tanhbuf[tbase + i];
  int f = i / N, n = i % N;
  float r = fminf(fmaxf(t / a, -1.0f), 1.0f) * 127.0f;
  dst[n * F + f] = rintf(r) * a / 127.0f;
}

// ---------------------------------------------------------------------------
// t_conv body (R15 structure): one 512-thread block per patch.
// ---------------------------------------------------------------------------
template <int CIN, int F, int S, int HIN, bool MUL>
__device__ __forceinline__ void tconv_body(
    const float* __restrict__ in, const float* __restrict__ in2,
    const float* __restrict__ wqt, float* __restrict__ out, float MST,
    int patch, int tid) {
  constexpr int N = CIN * 9;
  constexpr int NP = (N <= 512) ? 512 : 1024;
  constexpr int KP = NP / 512;
  constexpr int OH = (HIN - 1) / S + 1;
  constexpr int P = OH * OH;
  constexpr int T = 512;
  constexpr int NCH = N / 32;

  __shared__ __align__(16) unsigned long long pk[NP];
  __shared__ float sval[N + 1];
  __shared__ unsigned short sidx[N];
  __shared__ float wbuf[2][32 * F];
  __shared__ float wc[NCH][F];
  __shared__ float iwc[NCH][F];
  __shared__ float pmin[F * NCH];

  int b = patch / P, p = patch % P;
  int ph = p / OH, pw = p % OH;

  // Phase 0: patch keys (+inf pad beyond N)
  for (int n = tid; n < NP; n += T) {
    if (n < N) {
      int c = n / 9, kk = n % 9, kh = kk / 3, kw = kk % 3;
      int r = ph * S + kh - 1, cc = pw * S + kw - 1;
      float v = 0.0f;
      if (r >= 0 && r < HIN && cc >= 0 && cc < HIN) {
        int q = ((b * CIN + c) * HIN + r) * HIN + cc;
        v = MUL ? __fmul_rn(in[q], in2[q]) : in[q];
      }
      pk[n] = packkey((v < 0.1f) ? MST : v, n);
    } else {
      pk[n] = ~0ull;
    }
  }
  if (tid == 0) sval[N] = 1.0f;
  __syncthreads();

  // Phase 1: bitonic sort
  if constexpr (KP == 1) {
    unsigned long long k0 = pk[tid];
    __syncthreads();
    for (int lk = 1; lk <= 9; ++lk) {
      for (int lj = lk - 1; lj >= 0; --lj) {
        int j = 1 << lj;
        bool up = ((tid >> lk) & 1) == 0;
        bool wmin = (((tid & j) == 0) == up);
        unsigned long long o;
        if (lj >= 6) {
          pk[tid] = k0;
          __syncthreads();
          o = pk[tid ^ j];
          __syncthreads();
        } else {
          o = __shfl_xor(k0, j, 64);
        }
        k0 = wmin ? (k0 < o ? k0 : o) : (k0 > o ? k0 : o);
      }
    }
    if (tid < N) {
      sval[tid] = unpackval(k0);
      sidx[tid] = (unsigned short)(k0 & 0xffffull);
    }
  } else {
    unsigned long long k0 = pk[2 * tid], k1 = pk[2 * tid + 1];
    __syncthreads();
    for (int lk = 1; lk <= 10; ++lk) {
      for (int lj = lk - 1; lj >= 0; --lj) {
        bool up = ((tid >> (lk - 1)) & 1) == 0;
        if (lj == 0) {
          if ((k0 > k1) == up) { unsigned long long t2 = k0; k0 = k1; k1 = t2; }
        } else {
          int tj = 1 << (lj - 1);
          bool wmin = (((tid & tj) == 0) == up);
          unsigned long long o0, o1;
          if (lj >= 7) {
            pk[tid] = k0; pk[512 + tid] = k1;
            __syncthreads();
            o0 = pk[tid ^ tj]; o1 = pk[512 + (tid ^ tj)];
            __syncthreads();
          } else {
            o0 = __shfl_xor(k0, tj, 64);
            o1 = __shfl_xor(k1, tj, 64);
          }
          k0 = wmin ? (k0 < o0 ? k0 : o0) : (k0 > o0 ? k0 : o0);
          k1 = wmin ? (k1 < o1 ? k1 : o1) : (k1 > o1 ? k1 : o1);
        }
      }
    }
    int i0 = tid * 2;
    if (i0 < N) {
      sval[i0] = unpackval(k0);
      sidx[i0] = (unsigned short)(k0 & 0xffffull);
    }
    if (i0 + 1 < N) {
      sval[i0 + 1] = unpackval(k1);
      sidx[i0 + 1] = (unsigned short)(k1 & 0xffffull);
    }
  }
  __syncthreads();

  // Phase 2a: stage chunk 0 (all threads)
  for (int t = tid; t < 32 * F; t += T) {
    int q = t / F, f = t % F;
    wbuf[0][t] = wqt[(int)sidx[q] * F + f];
  }
  __syncthreads();

  // Phase 2b: pass A — wave 0 chains, other waves stage next chunk
  float wsum = 0.0f, iwsum = 0.0f;
  for (int c = 0; c < NCH; ++c) {
    if (tid >= 64 && c + 1 < NCH) {
      int i0n = (c + 1) * 32;
      float* nb = wbuf[(c + 1) & 1];
      for (int t = tid - 64; t < 32 * F; t += (T - 64)) {
        int q = t / F, f = t % F;
        nb[t] = wqt[(int)sidx[i0n + q] * F + f];
      }
    }
    if (tid < F) {
      const float* wb = wbuf[c & 1];
      wc[c][tid] = wsum;
      iwc[c][tid] = iwsum;
      int i0 = c * 32;
#pragma unroll
      for (int q0 = 0; q0 < 32; q0 += 8) {
        float w8[8], s8[8];
#pragma unroll
        for (int r = 0; r < 8; ++r) {
          w8[r] = wb[(q0 + r) * F + tid];
          s8[r] = sval[i0 + q0 + r];
        }
#pragma unroll
        for (int r = 0; r < 8; ++r) {
          wsum = __fadd_rn(wsum, w8[r]);
          iwsum = __fadd_rn(iwsum, __fmul_rn(s8[r], w8[r]));
        }
      }
    }
    __syncthreads();
  }

  // Phase 2c: replay — NCH*F parallel tasks, bit-exact per element
  for (int task = tid; task < NCH * F; task += T) {
    int c = task / F, f = task % F;
    float ws = wc[c][f], iws = iwc[c][f], omin = 3.402823466e38f;
    int i0 = c * 32;
#pragma unroll
    for (int q0 = 0; q0 < 32; q0 += 8) {
      float wv8[8], sv8[8], nv8[8];
#pragma unroll
      for (int r = 0; r < 8; ++r) {
        int i = i0 + q0 + r;
        wv8[r] = wqt[(int)sidx[i] * F + f];
        sv8[r] = sval[i];
        nv8[r] = sval[i + 1];
      }
#pragma unroll
      for (int r = 0; r < 8; ++r) {
        ws = __fadd_rn(ws, wv8[r]);
        iws = __fadd_rn(iws, __fmul_rn(sv8[r], wv8[r]));
        float den = fminf(fmaxf(__fadd_rn(ws, -1.0f), 1e-10f), 1e10f);
        float oa = iws / den;
        float o = (ws < 1.0f) ? MST : oa;
        o = (o < sv8[r]) ? MST : o;
        o = (o > nv8[r]) ? MST : o;  // t_linear_c: strict >
        omin = fminf(omin, o);
      }
    }
    pmin[f * NCH + c] = omin;
  }
  __syncthreads();

  // Phase 2d: min across chunks (order-free), write out
  if (tid < F) {
    float m2 = pmin[tid * NCH];
#pragma unroll
    for (int c = 1; c < NCH; ++c) m2 = fminf(m2, pmin[tid * NCH + c]);
    out[(b * F + tid) * P + p] = m2;
  }
}

template <int CIN, int F, int S, int HIN, bool MUL>
__global__ __launch_bounds__(512, 1) void tconv_kernel(
    const float* __restrict__ in, const float* __restrict__ in2,
    const float* __restrict__ wqt, float* __restrict__ out, float MST) {
  tconv_body<CIN, F, S, HIN, MUL>(in, in2, wqt, out, MST, blockIdx.x, threadIdx.x);
}

// ---------------------------------------------------------------------------
// t4 fused: blocks [0,512) tconv layer4; blocks [512,544) mp3mul z3*m1 -> m3.
// ---------------------------------------------------------------------------
__global__ __launch_bounds__(512, 1) void t4f_kernel(
    const float* __restrict__ z3, const float* __restrict__ m1,
    const float* __restrict__ wq4, float* __restrict__ z4,
    float* __restrict__ m3, float MST) {
  int blk = blockIdx.x;
  if (blk < 512) {
    tconv_body<32, 64, 2, 16, true>(z3, m1, wq4, z4, MST, blk, threadIdx.x);
    return;
  }
  // mp3mul: min over 3x3 of (z3*m1), H=16, BC=256, total 16384
  int idx = (blk - 512) * 512 + threadIdx.x;
  if (idx >= 16384) return;
  int OH = 8;
  int j = idx % OH, i = (idx / OH) % OH, bc = idx / (OH * OH);
  float mn = 100000.0f;
  for (int di = 0; di < 3; ++di) {
    int r = 2 * i - 1 + di;
    if (r < 0 || r >= 16) continue;
    for (int dj = 0; dj < 3; ++dj) {
      int cc = 2 * j - 1 + dj;
      if (cc < 0 || cc >= 16) continue;
      int q = bc * 256 + r * 16 + cc;
      mn = fminf(mn, __fmul_rn(z3[q], m1[q]));
    }
  }
  m3[idx] = mn;
}

// ---------------------------------------------------------------------------
// Bitonic pass, fully compile-time specialized (LK = stage, LJ = pass).
// ---------------------------------------------------------------------------
template <int LK, int LJ>
__device__ __forceinline__ void bpass(unsigned long long (&k)[8],
                                      unsigned long long* keys,
                                      int tid, int lane) {
  if constexpr (LJ >= 9) {
    constexpr int pm = 1 << (LJ - 3);
#pragma unroll
    for (int m = 0; m < 8; ++m) keys[m * 512 + tid] = k[m];
    __syncthreads();
    bool lower = ((tid & pm) == 0);
    bool up = (((tid >> (LK - 3)) & 1) == 0);
    bool wmin = (lower == up);
#pragma unroll
    for (int m = 0; m < 8; ++m) {
      unsigned long long o = keys[m * 512 + (tid ^ pm)];
      unsigned long long mine = k[m];
      k[m] = wmin ? (mine < o ? mine : o) : (mine > o ? mine : o);
    }
    __syncthreads();
  } else if constexpr (LJ >= 3) {
    constexpr int lm = 1 << (LJ - 3);
    bool lower = ((lane & lm) == 0);
    bool up = (((tid >> (LK - 3)) & 1) == 0);
    bool wmin = (lower == up);
#pragma unroll
    for (int m = 0; m < 8; ++m) {
      unsigned long long o = __shfl_xor(k[m], lm, 64);
      unsigned long long mine = k[m];
      k[m] = wmin ? (mine < o ? mine : o) : (mine > o ? mine : o);
    }
  } else {
    constexpr int j = 1 << LJ;
#pragma unroll
    for (int m = 0; m < 8; ++m) {
      if ((m & j) == 0) {
        int i = (tid << 3) + m;
        bool up = (((i >> LK) & 1) == 0);
        unsigned long long a = k[m], c2 = k[m | j];
        if ((a > c2) == up) { k[m] = c2; k[m | j] = a; }
      }
    }
  }
}

template <int LK, int LJ>
__device__ __forceinline__ void bpasses(unsigned long long (&k)[8],
                                        unsigned long long* keys,
                                        int tid, int lane) {
  bpass<LK, LJ>(k, keys, tid, lane);
  if constexpr (LJ > 0) bpasses<LK, LJ - 1>(k, keys, tid, lane);
}

template <int LK>
__device__ __forceinline__ void bstages(unsigned long long (&k)[8],
                                        unsigned long long* keys,
                                        int tid, int lane) {
  bpasses<LK, LK - 1>(k, keys, tid, lane);
  if constexpr (LK < 12) bstages<LK + 1>(k, keys, tid, lane);
}

// ---------------------------------------------------------------------------
// FC sort: 8 blocks x 512, unrolled register bitonic; writes sval/sidx.
// ---------------------------------------------------------------------------
__global__ __launch_bounds__(512, 1) void fc_sort_kernel(
    const float* __restrict__ z5, const float* __restrict__ m3,
    float* __restrict__ svalG, unsigned short* __restrict__ sidxG) {
  __shared__ __align__(16) unsigned long long keys[4096];
  int b = blockIdx.x, tid = threadIdx.x, lane = tid & 63;

  unsigned long long k[8];
  {
    int c = tid >> 3, p0 = (tid << 3) & 63;
    const float4* z4p = (const float4*)(z5 + (b * 64 + c) * 64 + p0);
    const float4* m4p = (const float4*)(m3 + (b * 32 + (c & 31)) * 64 + p0);
    float4 za = z4p[0], zb = z4p[1], ma = m4p[0], mb = m4p[1];
    int n0 = tid << 3;
    k[0] = packkey(__fmul_rn(za.x, ma.x), n0 + 0);
    k[1] = packkey(__fmul_rn(za.y, ma.y), n0 + 1);
    k[2] = packkey(__fmul_rn(za.z, ma.z), n0 + 2);
    k[3] = packkey(__fmul_rn(za.w, ma.w), n0 + 3);
    k[4] = packkey(__fmul_rn(zb.x, mb.x), n0 + 4);
    k[5] = packkey(__fmul_rn(zb.y, mb.y), n0 + 5);
    k[6] = packkey(__fmul_rn(zb.z, mb.z), n0 + 6);
    k[7] = packkey(__fmul_rn(zb.w, mb.w), n0 + 7);
  }

  bstages<1>(k, keys, tid, lane);

  {
    float4 v0, v1;
    v0.x = unpackval(k[0]); v0.y = unpackval(k[1]);
    v0.z = unpackval(k[2]); v0.w = unpackval(k[3]);
    v1.x = unpackval(k[4]); v1.y = unpackval(k[5]);
    v1.z = unpackval(k[6]); v1.w = unpackval(k[7]);
    float* svalRow = svalG + b * 4104;
    ((float4*)svalRow)[tid * 2] = v0;
    ((float4*)svalRow)[tid * 2 + 1] = v1;
    ushort si[8];
#pragma unroll
    for (int m = 0; m < 8; ++m) si[m] = (unsigned short)(k[m] & 0xffffull);
    ((ulong2*)(sidxG + b * 4096))[tid] = *(ulong2*)si;
    if (tid == 0) svalRow[4096] = 1.0f;
  }
}

// ---------------------------------------------------------------------------
// FC scan v3: 80 blocks (batch x neuron) x 512 threads. (unchanged — passing)
// ---------------------------------------------------------------------------
__global__ __launch_bounds__(512, 1) void fc_scan2_kernel(
    const float* __restrict__ svalG, const unsigned short* __restrict__ sidxG,
    const float* __restrict__ wfcT, float* __restrict__ out) {
  constexpr int NN = 4096;
  __shared__ __align__(16) float sval[NN + 1];
  __shared__ __align__(16) float pairs[NN * 2];
  __shared__ float wc[128], iwc[128];
  __shared__ float pmin[128];

  int blk = blockIdx.x;
  int b = blk / 10, f = blk % 10;
  int tid = threadIdx.x;
  const float* svalRow = svalG + b * 4104;

  for (int t = tid; t < 1024; t += 512)
    ((float4*)sval)[t] = ((const float4*)svalRow)[t];
  if (tid == 0) sval[NN] = svalRow[4096];

  ushort si[8];
  *(ulong2*)si = ((const ulong2*)(sidxG + b * 4096))[tid];
  float wv[8];
#pragma unroll
  for (int u = 0; u < 8; ++u) wv[u] = wfcT[(int)si[u] * 10 + f];
  __syncthreads();

  {
    int n0 = tid * 8;
    float4 pw[4];
#pragma unroll
    for (int u = 0; u < 4; ++u) {
      float wa = wv[2 * u], wb2 = wv[2 * u + 1];
      pw[u].x = wa;
      pw[u].y = __fmul_rn(sval[n0 + 2 * u], wa);
      pw[u].z = wb2;
      pw[u].w = __fmul_rn(sval[n0 + 2 * u + 1], wb2);
    }
#pragma unroll
    for (int u = 0; u < 4; ++u) ((float4*)pairs)[tid * 4 + u] = pw[u];
  }
  __syncthreads();

  if (tid == 0) {
    float wsum = 0.0f, iwsum = 0.0f;
    float4 A[16], B[16];
    auto LD_A = [&](int c) {
      const float4* p4 = (const float4*)pairs + c * 16;
#pragma unroll
      for (int q = 0; q < 16; ++q) A[q] = p4[q];
    };
    auto LD_B = [&](int c) {
      const float4* p4 = (const float4*)pairs + c * 16;
#pragma unroll
      for (int q = 0; q < 16; ++q) B[q] = p4[q];
    };
    auto ACC_A = [&]() {
#pragma unroll
      for (int q = 0; q < 16; ++q) {
        wsum = __fadd_rn(wsum, A[q].x); iwsum = __fadd_rn(iwsum, A[q].y);
        wsum = __fadd_rn(wsum, A[q].z); iwsum = __fadd_rn(iwsum, A[q].w);
      }
    };
    auto ACC_B = [&]() {
#pragma unroll
      for (int q = 0; q < 16; ++q) {
        wsum = __fadd_rn(wsum, B[q].x); iwsum = __fadd_rn(iwsum, B[q].y);
        wsum = __fadd_rn(wsum, B[q].z); iwsum = __fadd_rn(iwsum, B[q].w);
      }
    };
    LD_A(0);
    for (int c = 0; c < 128; c += 2) {
      wc[c] = wsum; iwc[c] = iwsum;
      if (c + 1 < 128) LD_B(c + 1);
      ACC_A();
      wc[c + 1] = wsum; iwc[c + 1] = iwsum;
      if (c + 2 < 128) LD_A(c + 2);
      ACC_B();
    }
  }
  __syncthreads();

  const float MST = 4.0f * E32;
  if (tid < 128) {
    float ws = wc[tid], iws = iwc[tid], omin = 3.402823466e38f;
    int i0 = tid * 32;
    for (int q0 = 0; q0 < 32; q0 += 8) {
      float w8[8], m8[8], sv8[8], nv8[8];
#pragma unroll
      for (int r = 0; r < 8; ++r) {
        int i = i0 + q0 + r;
        w8[r] = pairs[2 * i];
        m8[r] = pairs[2 * i + 1];
        sv8[r] = sval[i];
        nv8[r] = sval[i + 1];
      }
#pragma unroll
      for (int r = 0; r < 8; ++r) {
        ws = __fadd_rn(ws, w8[r]);
        iws = __fadd_rn(iws, m8[r]);
        float den = fminf(fmaxf(__fadd_rn(ws, -1.0f), 1e-10f), 1e10f);
        float oa = iws / den;
        float o = (ws < 1.0f) ? MST : oa;
        o = (o < sv8[r]) ? MST : o;
        o = (o >= nv8[r]) ? MST : o;  // t_linear: >=
        omin = fminf(omin, o);
      }
    }
    pmin[tid] = omin;
  }
  __syncthreads();

  if (tid == 0) {
    float m = pmin[0];
    for (int c = 1; c < 128; ++c) m = fminf(m, pmin[c]);
    out[b * 10 + f] = m;
  }
}

// ---------------------------------------------------------------------------
extern "C" void kernel_launch(void* const* d_in, const int* in_sizes, int n_in,
                              void* d_out, int out_size, void* d_ws, size_t ws_size,
                              hipStream_t stream) {
  const float* inp   = (const float*)d_in[0];
  const float* w1    = (const float*)d_in[1];
  const float* bn_g  = (const float*)d_in[2];
  const float* bn_b  = (const float*)d_in[3];
  const float* bn_m  = (const float*)d_in[4];
  const float* bn_v  = (const float*)d_in[5];
  const float* w2    = (const float*)d_in[6];
  const float* w3    = (const float*)d_in[7];
  const float* w4    = (const float*)d_in[8];
  const float* w5    = (const float*)d_in[9];
  const float* wfc   = (const float*)d_in[10];
  float* out = (float*)d_out;

  float* ws = (float*)d_ws;
  float* wq2 = ws + 16;          // 9216
  float* wq3 = wq2 + 9216;       // 9216
  float* wq4 = wq3 + 9216;       // 18432
  float* wq5 = wq4 + 18432;      // 36864
  float* z1  = wq5 + 36864;      // 262144
  float* m1  = z1 + 262144;      // 65536
  float* z2  = m1 + 65536;       // 65536
  float* z3  = z2 + 65536;       // 65536
  float* m3  = z3 + 65536;       // 16384
  float* z4  = m3 + 16384;       // 32768
  float* z5  = z4 + 32768;       // 32768
  float* tanhbuf  = z5 + 32768;  // 73728
  float* partials = tanhbuf + 73728;  // 288 (pad 512)
  float* wfcT = partials + 512;  // 40960
  float* svalG = wfcT + 40960;   // 8*4104 = 32832
  unsigned short* sidxG = (unsigned short*)(svalG + 32832);  // 8*4096 u16

  pre1_kernel<<<1312, 256, 0, stream>>>(w2, w3, w4, w5, tanhbuf, partials,
                                        inp, w1, bn_g, bn_b, bn_m, bn_v, z1);
  pre2_kernel<<<704, 256, 0, stream>>>(tanhbuf, partials, wq2, wq3, wq4, wq5,
                                       wfc, wfcT, z1, m1);

  tconv_kernel<32, 32, 2, 32, false><<<8 * 256, 512, 0, stream>>>(z1, nullptr, wq2, z2, E32);
  tconv_kernel<32, 32, 1, 16, false><<<8 * 256, 512, 0, stream>>>(z2, nullptr, wq3, z3, E32);
  t4f_kernel<<<544, 512, 0, stream>>>(z3, m1, wq4, z4, m3, 2.0f * E32);
  tconv_kernel<64, 64, 1, 8, false><<<8 * 64, 512, 0, stream>>>(z4, nullptr, wq5, z5, 2.0f * E32);

  fc_sort_kernel<<<8, 512, 0, stream>>>(z5, m3, svalG, sidxG);
  fc_scan2_kernel<<<80, 512, 0, stream>>>(svalG, sidxG, wfcT, out);
}